// Round 7
// baseline (739.844 us; speedup 1.0000x reference)
//
#include <hip/hip_runtime.h>
#include <hip/hip_bf16.h>
#include <math.h>

typedef unsigned short u16;
typedef __bf16 bf16x8 __attribute__((ext_vector_type(8)));
typedef short s16x4 __attribute__((ext_vector_type(4)));
typedef float f32x4 __attribute__((ext_vector_type(4)));

#define B_   8
#define NQ   1024
#define NC   2048
#define IND  768
#define DIM  384
#define NH   6
#define HD   64
#define HID  3072

__device__ __forceinline__ u16 f2b(float f){
  unsigned int x = __float_as_uint(f);
  return (u16)((x + 0x7fffu + ((x >> 16) & 1u)) >> 16);
}

__device__ __forceinline__ void gl_lds16(const u16* g, u16* l){
  __builtin_amdgcn_global_load_lds(
    (const __attribute__((address_space(1))) unsigned int*)g,
    (__attribute__((address_space(3))) unsigned int*)l, 16, 0, 0);
}

// ---- weight convert+transpose: W (K x N) fp32 -> Wt (N x K) bf16 ----
__global__ void wtrans_kernel(const float* __restrict__ W, u16* __restrict__ Wt,
                              int K, int N){
  __shared__ float tile[32][33];
  int n0 = blockIdx.x * 32, k0 = blockIdx.y * 32;
  int tx = threadIdx.x, ty = threadIdx.y;   // 32 x 8
  #pragma unroll
  for(int i=0;i<4;i++) tile[ty*4+i][tx] = W[(size_t)(k0+ty*4+i)*N + n0 + tx];
  __syncthreads();
  #pragma unroll
  for(int i=0;i<4;i++) Wt[(size_t)(n0+ty*4+i)*K + k0 + tx] = f2b(tile[tx][ty*4+i]);
}

// ---- V transpose: KV (b, m, 2, h, d) -> Vt (b, h, d, m) bf16 ----
__global__ void vtrans_kernel(const u16* __restrict__ KV, u16* __restrict__ Vt, int M){
  __shared__ u16 t[64][72];
  int bh = blockIdx.y; int b = bh / NH, h = bh % NH;
  int m0 = blockIdx.x * 64;
  int tx = threadIdx.x & 63, ty = threadIdx.x >> 6;   // 64 x 4
  #pragma unroll
  for(int i=0;i<16;i++){
    int mm = ty*16+i;
    t[mm][tx] = KV[(size_t)(b*M + m0 + mm)*(2*DIM) + DIM + h*HD + tx];
  }
  __syncthreads();
  #pragma unroll
  for(int i=0;i<16;i++){
    int dd = ty*16+i;
    Vt[(size_t)(bh*HD + dd)*M + m0 + tx] = t[tx][dd];
  }
}

// ---- layernorm over rows of 768: fp32 in -> bf16 out (+optional fp32 out) ----
template<bool ALSO_F32>
__global__ void ln_kernel(const float* __restrict__ x, const float* __restrict__ w,
                          const float* __restrict__ bia, u16* __restrict__ yb,
                          float* __restrict__ yf){
  int row = blockIdx.x;
  const float* xr = x + (size_t)row * IND;
  int t = threadIdx.x;
  float v[3];
  v[0] = xr[t]; v[1] = xr[t+256]; v[2] = xr[t+512];
  float s  = v[0]+v[1]+v[2];
  float sq = v[0]*v[0]+v[1]*v[1]+v[2]*v[2];
  #pragma unroll
  for(int o=1;o<64;o<<=1){ s += __shfl_xor(s, o, 64); sq += __shfl_xor(sq, o, 64); }
  __shared__ float ss[4], ssq[4];
  int wid = t >> 6;
  if((t&63)==0){ ss[wid]=s; ssq[wid]=sq; }
  __syncthreads();
  s  = ss[0]+ss[1]+ss[2]+ss[3];
  sq = ssq[0]+ssq[1]+ssq[2]+ssq[3];
  float mean = s * (1.0f/IND);
  float var  = sq * (1.0f/IND) - mean*mean;
  float rs   = rsqrtf(var + 1e-5f);
  #pragma unroll
  for(int i=0;i<3;i++){
    int idx = t + i*256;
    float y = (v[i]-mean)*rs*w[idx] + bia[idx];
    yb[(size_t)row*IND + idx] = f2b(y);
    if(ALSO_F32) yf[(size_t)row*IND + idx] = y;
  }
}

// ---- NT GEMM: C(rows x N) = A(rows x K) @ Wt(N x K)^T, bf16 MFMA 16x16x32 ----
// Ring-buffered pipeline, ONE barrier per K-step, counted vmcnt (T3/T4).
// R5/R6 A/B showed prefetch DEPTH is the lever (depth-3 = 78us, depth-2 =
// 83us on the K=3072 down-proj), while the 2nd barrier is free to drop.
// TN=64: DEPTH=4 ring -> 3 stages in flight (49 KB LDS, still 3 blocks/CU).
// TN=128: DEPTH=3 ring -> 2 in flight (4 buffers would halve occupancy).
// stage(t+DEPTH-1) targets a buffer never being computed this step; the
// overwritten buffer's ds_reads retired before the previous barrier.
// OUTM: 0 = bf16 store, 1 = fp32 store, 2 = fp32 += (single writer),
//       3 = bf16 store scaled by 0.125 (softmax d^-0.5 folded into Q)
template<int TN, int OUTM, bool BIAS, bool GELU_>
__global__ __launch_bounds__(256) void gemm_bt(const u16* __restrict__ A,
    const u16* __restrict__ Wt, const float* __restrict__ bias,
    void* __restrict__ C, int K, int N){
  constexpr int JT = TN / 32;                 // b-tiles per wave (4 or 2)
  constexpr int DEPTH = (TN == 64) ? 4 : 3;
  __shared__ __align__(16) u16 As[DEPTH][128][32];
  __shared__ __align__(16) u16 Bs[DEPTH][TN][32];
  int rowblk = blockIdx.x * 128, colblk = blockIdx.y * TN;
  int tid = threadIdx.x;
  int lane = tid & 63, wv = tid >> 6;
  int wm = (wv >> 1) * 64, wn = (wv & 1) * (16*JT);
  int l16 = lane & 15, quad = lane >> 4;
  f32x4 acc[4][JT] = {};
  int sr = lane >> 2;
  int sc = (((lane & 3) ^ ((lane >> 3) & 3)) * 8);   // staged chunk (XOR swizzle)
  int rc = ((quad ^ ((l16 >> 1) & 3)) * 8);          // read-back column
  const u16* Ap = A  + (size_t)(rowblk + wv*16 + sr) * K + sc;
  const u16* Bp = Wt + (size_t)(colblk + wv*16 + sr) * K + sc;

  auto stage = [&](int step, int bi){
    int kt = step * 32;
    gl_lds16(Ap + kt,                 &As[bi][wv*16][0]);
    gl_lds16(Ap + (size_t)64*K + kt,  &As[bi][64 + wv*16][0]);
    gl_lds16(Bp + kt,                 &Bs[bi][wv*16][0]);
    if constexpr (TN == 128)
      gl_lds16(Bp + (size_t)64*K + kt, &Bs[bi][64 + wv*16][0]);
  };
  auto compute = [&](int bi){
    bf16x8 af[4], bfr[JT];
    #pragma unroll
    for(int i=0;i<4;i++)  af[i]  = *(const bf16x8*)&As[bi][wm + i*16 + l16][rc];
    #pragma unroll
    for(int j=0;j<JT;j++) bfr[j] = *(const bf16x8*)&Bs[bi][wn + j*16 + l16][rc];
    #pragma unroll
    for(int i=0;i<4;i++)
      #pragma unroll
      for(int j=0;j<JT;j++)
        acc[i][j] = __builtin_amdgcn_mfma_f32_16x16x32_bf16(af[i], bfr[j], acc[i][j], 0, 0, 0);
  };

  int nt = K / 32;            // 12 / 24 / 96 for our shapes, always >= DEPTH
  stage(0, 0); stage(1, 1);
  if constexpr (DEPTH == 4) stage(2, 2);

  int bi = 0;
  for(int t = 0; t < nt - (DEPTH-1); ++t){
    // wait for the oldest stage only; DEPTH-2 stages stay in flight
    if constexpr (DEPTH == 4)      asm volatile("s_waitcnt vmcnt(6)" ::: "memory");
    else if constexpr (TN == 128)  asm volatile("s_waitcnt vmcnt(4)" ::: "memory");
    else                           asm volatile("s_waitcnt vmcnt(3)" ::: "memory");
    __builtin_amdgcn_s_barrier();
    __builtin_amdgcn_sched_barrier(0);
    stage(t + DEPTH - 1, bi == 0 ? DEPTH-1 : bi - 1);
    compute(bi);
    bi = (bi == DEPTH-1) ? 0 : bi + 1;
  }
  // tail: DEPTH-1 remaining computes, draining the pipeline
  if constexpr (DEPTH == 4){
    asm volatile("s_waitcnt vmcnt(6)" ::: "memory");
    __builtin_amdgcn_s_barrier();
    __builtin_amdgcn_sched_barrier(0);
    compute(bi); bi = (bi == DEPTH-1) ? 0 : bi + 1;
    asm volatile("s_waitcnt vmcnt(3)" ::: "memory");
    __builtin_amdgcn_s_barrier();
    __builtin_amdgcn_sched_barrier(0);
    compute(bi); bi = (bi == DEPTH-1) ? 0 : bi + 1;
    asm volatile("s_waitcnt vmcnt(0)" ::: "memory");
    __builtin_amdgcn_s_barrier();
    __builtin_amdgcn_sched_barrier(0);
    compute(bi);
  } else {
    if constexpr (TN == 128) asm volatile("s_waitcnt vmcnt(4)" ::: "memory");
    else                     asm volatile("s_waitcnt vmcnt(3)" ::: "memory");
    __builtin_amdgcn_s_barrier();
    __builtin_amdgcn_sched_barrier(0);
    compute(bi); bi = (bi == DEPTH-1) ? 0 : bi + 1;
    asm volatile("s_waitcnt vmcnt(0)" ::: "memory");
    __builtin_amdgcn_s_barrier();
    __builtin_amdgcn_sched_barrier(0);
    compute(bi);
  }

  #pragma unroll
  for(int i=0;i<4;i++){
    #pragma unroll
    for(int j=0;j<JT;j++){
      int grow = rowblk + wm + i*16 + quad*4;
      int gcol = colblk + wn + j*16 + l16;
      float bv = BIAS ? bias[gcol] : 0.0f;
      #pragma unroll
      for(int rg=0; rg<4; rg++){
        float vval = acc[i][j][rg] + bv;
        if(GELU_) vval = 0.5f * vval * (1.0f + erff(vval * 0.70710678118f));
        size_t idx = (size_t)(grow + rg) * N + gcol;
        if(OUTM == 0)      ((u16*)C)[idx]   = f2b(vval);
        else if(OUTM == 3) ((u16*)C)[idx]   = f2b(vval * 0.125f);
        else if(OUTM == 1) ((float*)C)[idx] = vval;
        else               ((float*)C)[idx] += vval;
      }
    }
  }
}

// ---- flash attention v5 ----
// Round-1 proven synchronous global->LDS staging (short live ranges, no
// spill: rounds 3/4 showed the split reg-staging arrays get forced to
// scratch regardless of launch_bounds -> 320 MB scratch writes).
// Kept VALU cuts: QK^T via mfma 16x16x32 (b128 LDS reads, half the QK MFMA
// issues), Q pre-scaled by d^-0.5 in its GEMM, p = __expf(z), f2b P-pack.
__global__ __launch_bounds__(256) void attn_kernel(const u16* __restrict__ Q,
    const u16* __restrict__ KV, const u16* __restrict__ Vtg,
    u16* __restrict__ AO, int M){
  __shared__ __align__(16) u16 Ks[128][72];   // [ctx][d]  144B stride (16B-aligned)
  __shared__ __align__(16) u16 Vs[64][132];   // [d][ctx]  +4 pad
  int tid = threadIdx.x, lane = tid & 63, wv = tid >> 6;
  int bh = blockIdx.x % (B_*NH);              // XCD = bh % 8 for all its q-tiles
  int qt = blockIdx.x / (B_*NH);
  int h = bh % NH, b = bh / NH;
  int l16 = lane & 15, quad = lane >> 4;

  // Q fragment for 16x16x32: lane (l16,quad) holds d = s*32 + quad*8 .. +7
  bf16x8 qf[2];
  const u16* qp = Q + (size_t)(b*NQ + qt*64 + wv*16 + l16) * DIM + h*HD + quad*8;
  qf[0] = *(const bf16x8*)(qp);
  qf[1] = *(const bf16x8*)(qp + 32);

  f32x4 o[4] = {};
  float lacc = 0.f;

  for(int cb = 0; cb < M; cb += 128){
    __syncthreads();
    #pragma unroll
    for(int it=0; it<4; it++){
      int idx = tid + it*256;
      int row = idx >> 3, c8 = (idx & 7) * 8;
      *(int4*)&Ks[row][c8] =
        *(const int4*)(KV + (size_t)(b*M + cb + row)*(2*DIM) + h*HD + c8);
    }
    #pragma unroll
    for(int it=0; it<4; it++){
      int idx = tid + it*256;
      int dd = idx >> 4, c8 = (idx & 15) * 8;
      *(int4*)&Vs[dd][c8] =
        *(const int4*)(Vtg + (size_t)(bh*HD + dd)*M + cb + c8);
    }
    __syncthreads();

    s16x4 pp[8];
    #pragma unroll
    for(int cc=0; cc<8; cc++){
      f32x4 z = {};
      #pragma unroll
      for(int s=0;s<2;s++){
        bf16x8 kf = *(const bf16x8*)&Ks[cc*16 + l16][quad*8 + s*32];
        z = __builtin_amdgcn_mfma_f32_16x16x32_bf16(kf, qf[s], z, 0,0,0);
      }
      float p0 = __expf(z[0]), p1 = __expf(z[1]);
      float p2 = __expf(z[2]), p3 = __expf(z[3]);
      lacc += (p0+p1) + (p2+p3);
      s16x4 pb;
      pb[0] = (short)f2b(p0); pb[1] = (short)f2b(p1);
      pb[2] = (short)f2b(p2); pb[3] = (short)f2b(p3);
      pp[cc] = pb;
    }
    #pragma unroll
    for(int dn=0;dn<4;dn++){
      #pragma unroll
      for(int tt=0;tt<8;tt++){
        s16x4 vf = *(const s16x4*)&Vs[dn*16 + l16][quad*4 + tt*16];
        o[dn] = __builtin_amdgcn_mfma_f32_16x16x16bf16_1k(vf, pp[tt], o[dn], 0,0,0);
      }
    }
  }

  lacc += __shfl_xor(lacc, 16, 64);
  lacc += __shfl_xor(lacc, 32, 64);
  float rl = 1.0f / lacc;

  u16* aop = AO + (size_t)(b*NQ + qt*64 + wv*16 + l16) * DIM + h*HD + quad*4;
  #pragma unroll
  for(int dn=0;dn<4;dn++){
    s16x4 ob;
    #pragma unroll
    for(int r=0;r<4;r++) ob[r] = (short)f2b(o[dn][r] * rl);
    *(s16x4*)(aop + dn*16) = ob;
  }
}

extern "C" void kernel_launch(void* const* d_in, const int* in_sizes, int n_in,
                              void* d_out, int out_size, void* d_ws, size_t ws_size,
                              hipStream_t stream){
  const float* query   = (const float*)d_in[0];
  const float* context = (const float*)d_in[1];
  const float* ln_w  = (const float*)d_in[2];
  const float* ln_b  = (const float*)d_in[3];
  const float* a1_wq = (const float*)d_in[4];
  const float* a1_wkv= (const float*)d_in[5];
  const float* a1_wp = (const float*)d_in[6];
  const float* a1_bp = (const float*)d_in[7];
  const float* m1_w1 = (const float*)d_in[8];
  const float* m1_b1 = (const float*)d_in[9];
  const float* m1_w2 = (const float*)d_in[10];
  const float* m1_b2 = (const float*)d_in[11];
  const float* a2_wq = (const float*)d_in[12];
  const float* a2_wkv= (const float*)d_in[13];
  const float* a2_wp = (const float*)d_in[14];
  const float* a2_bp = (const float*)d_in[15];
  const float* m2_w1 = (const float*)d_in[16];
  const float* m2_b1 = (const float*)d_in[17];
  const float* m2_w2 = (const float*)d_in[18];
  const float* m2_b2 = (const float*)d_in[19];
  (void)in_sizes; (void)n_in; (void)out_size; (void)ws_size;

  float* c_out = (float*)d_out;                    // output 0: c (8,1024,768) fp32
  float* q_out = c_out + (size_t)B_*NQ*IND;        // output 1: q (8,1024,768) fp32

  char* base = (char*)d_ws;
  size_t off = 0;
  auto alloc = [&](size_t elems)->u16*{
    u16* p = (u16*)(base + off);
    off += ((elems*2) + 255) & ~(size_t)255;
    return p;
  };
  u16* wq1t  = alloc((size_t)DIM*IND);
  u16* wkv1t = alloc((size_t)2*DIM*IND);
  u16* wp1t  = alloc((size_t)IND*DIM);
  u16* w11t  = alloc((size_t)HID*IND);
  u16* w21t  = alloc((size_t)IND*HID);
  u16* wq2t  = alloc((size_t)DIM*IND);
  u16* wkv2t = alloc((size_t)2*DIM*IND);
  u16* wp2t  = alloc((size_t)IND*DIM);
  u16* w12t  = alloc((size_t)HID*IND);
  u16* w22t  = alloc((size_t)IND*HID);
  u16* qn_b  = alloc((size_t)B_*NQ*IND);
  u16* cn_b  = alloc((size_t)B_*NC*IND);
  u16* Tb    = alloc((size_t)B_*NQ*IND);
  u16* Qb    = alloc((size_t)B_*NQ*DIM);
  u16* KVb   = alloc((size_t)B_*NC*2*DIM);
  u16* AOb   = alloc((size_t)B_*NQ*DIM);
  u16* Hb    = alloc((size_t)B_*NQ*HID);
  u16* Vtb   = Hb;   // alias: Hb idle during attention phases

  dim3 tb(32,8);
  wtrans_kernel<<<dim3(DIM/32,   IND/32), tb, 0, stream>>>(a1_wq,  wq1t,  IND, DIM);
  wtrans_kernel<<<dim3(2*DIM/32, IND/32), tb, 0, stream>>>(a1_wkv, wkv1t, IND, 2*DIM);
  wtrans_kernel<<<dim3(IND/32,   DIM/32), tb, 0, stream>>>(a1_wp,  wp1t,  DIM, IND);
  wtrans_kernel<<<dim3(HID/32,   IND/32), tb, 0, stream>>>(m1_w1,  w11t,  IND, HID);
  wtrans_kernel<<<dim3(IND/32,   HID/32), tb, 0, stream>>>(m1_w2,  w21t,  HID, IND);
  wtrans_kernel<<<dim3(DIM/32,   IND/32), tb, 0, stream>>>(a2_wq,  wq2t,  IND, DIM);
  wtrans_kernel<<<dim3(2*DIM/32, IND/32), tb, 0, stream>>>(a2_wkv, wkv2t, IND, 2*DIM);
  wtrans_kernel<<<dim3(IND/32,   DIM/32), tb, 0, stream>>>(a2_wp,  wp2t,  DIM, IND);
  wtrans_kernel<<<dim3(HID/32,   IND/32), tb, 0, stream>>>(m2_w1,  w12t,  IND, HID);
  wtrans_kernel<<<dim3(IND/32,   HID/32), tb, 0, stream>>>(m2_w2,  w22t,  HID, IND);

  ln_kernel<true ><<<B_*NQ, 256, 0, stream>>>(query,   ln_w, ln_b, qn_b, q_out);
  ln_kernel<false><<<B_*NC, 256, 0, stream>>>(context, ln_w, ln_b, cn_b, nullptr);

  // --- block 1: cross-attention ---
  gemm_bt<64,3,false,false><<<dim3(B_*NQ/128, DIM/64),  256, 0, stream>>>(qn_b, wq1t,  nullptr, Qb,  IND, DIM);
  gemm_bt<128,0,false,false><<<dim3(B_*NC/128, 2*DIM/128), 256, 0, stream>>>(cn_b, wkv1t, nullptr, KVb, IND, 2*DIM);
  vtrans_kernel<<<dim3(NC/64, B_*NH), 256, 0, stream>>>(KVb, Vtb, NC);
  attn_kernel<<<B_*NH*(NQ/64), 256, 0, stream>>>(Qb, KVb, Vtb, AOb, NC);
  gemm_bt<64,1,true,false><<<dim3(B_*NQ/128, IND/64), 256, 0, stream>>>(AOb, wp1t, a1_bp, c_out, DIM, IND);
  // --- MLP 1 ---
  ln_kernel<false><<<B_*NQ, 256, 0, stream>>>(c_out, ln_w, ln_b, Tb, nullptr);
  gemm_bt<128,0,true,true ><<<dim3(B_*NQ/128, HID/128), 256, 0, stream>>>(Tb, w11t, m1_b1, Hb, IND, HID);
  gemm_bt<64,2,true,false><<<dim3(B_*NQ/128, IND/64), 256, 0, stream>>>(Hb, w21t, m1_b2, c_out, HID, IND);
  // --- block 2: cross-attention (q reused, kv from LN(c)) ---
  ln_kernel<false><<<B_*NQ, 256, 0, stream>>>(c_out, ln_w, ln_b, Tb, nullptr);
  gemm_bt<64,3,false,false><<<dim3(B_*NQ/128, DIM/64),  256, 0, stream>>>(qn_b, wq2t,  nullptr, Qb,  IND, DIM);
  gemm_bt<64,0,false,false><<<dim3(B_*NQ/128, 2*DIM/64), 256, 0, stream>>>(Tb,   wkv2t, nullptr, KVb, IND, 2*DIM);
  vtrans_kernel<<<dim3(NQ/64, B_*NH), 256, 0, stream>>>(KVb, Vtb, NQ);
  attn_kernel<<<B_*NH*(NQ/64), 256, 0, stream>>>(Qb, KVb, Vtb, AOb, NQ);
  gemm_bt<64,2,true,false><<<dim3(B_*NQ/128, IND/64), 256, 0, stream>>>(AOb, wp2t, a2_bp, c_out, DIM, IND);
  // --- MLP 2 ---
  ln_kernel<false><<<B_*NQ, 256, 0, stream>>>(c_out, ln_w, ln_b, Tb, nullptr);
  gemm_bt<128,0,true,true ><<<dim3(B_*NQ/128, HID/128), 256, 0, stream>>>(Tb, w12t, m2_b1, Hb, IND, HID);
  gemm_bt<64,2,true,false><<<dim3(B_*NQ/128, IND/64), 256, 0, stream>>>(Hb, w22t, m2_b2, c_out, HID, IND);
}

// Round 8
// 689.884 us; speedup vs baseline: 1.0724x; 1.0724x over previous
//
#include <hip/hip_runtime.h>
#include <hip/hip_bf16.h>
#include <math.h>

typedef unsigned short u16;
typedef __bf16 bf16x8 __attribute__((ext_vector_type(8)));
typedef short s16x4 __attribute__((ext_vector_type(4)));
typedef float f32x4 __attribute__((ext_vector_type(4)));

#define B_   8
#define NQ   1024
#define NC   2048
#define IND  768
#define DIM  384
#define NH   6
#define HD   64
#define HID  3072

__device__ __forceinline__ u16 f2b(float f){
  unsigned int x = __float_as_uint(f);
  return (u16)((x + 0x7fffu + ((x >> 16) & 1u)) >> 16);
}

__device__ __forceinline__ void gl_lds16(const u16* g, u16* l){
  __builtin_amdgcn_global_load_lds(
    (const __attribute__((address_space(1))) unsigned int*)g,
    (__attribute__((address_space(3))) unsigned int*)l, 16, 0, 0);
}

// ---- weight convert+transpose: W (K x N) fp32 -> Wt (N x K) bf16 ----
__global__ void wtrans_kernel(const float* __restrict__ W, u16* __restrict__ Wt,
                              int K, int N){
  __shared__ float tile[32][33];
  int n0 = blockIdx.x * 32, k0 = blockIdx.y * 32;
  int tx = threadIdx.x, ty = threadIdx.y;   // 32 x 8
  #pragma unroll
  for(int i=0;i<4;i++) tile[ty*4+i][tx] = W[(size_t)(k0+ty*4+i)*N + n0 + tx];
  __syncthreads();
  #pragma unroll
  for(int i=0;i<4;i++) Wt[(size_t)(n0+ty*4+i)*K + k0 + tx] = f2b(tile[tx][ty*4+i]);
}

// ---- V transpose: KV (b, m, 2, h, d) -> Vt (b, h, d, m) bf16 ----
__global__ void vtrans_kernel(const u16* __restrict__ KV, u16* __restrict__ Vt, int M){
  __shared__ u16 t[64][72];
  int bh = blockIdx.y; int b = bh / NH, h = bh % NH;
  int m0 = blockIdx.x * 64;
  int tx = threadIdx.x & 63, ty = threadIdx.x >> 6;   // 64 x 4
  #pragma unroll
  for(int i=0;i<16;i++){
    int mm = ty*16+i;
    t[mm][tx] = KV[(size_t)(b*M + m0 + mm)*(2*DIM) + DIM + h*HD + tx];
  }
  __syncthreads();
  #pragma unroll
  for(int i=0;i<16;i++){
    int dd = ty*16+i;
    Vt[(size_t)(bh*HD + dd)*M + m0 + tx] = t[tx][dd];
  }
}

// ---- layernorm over rows of 768: fp32 in -> bf16 out (+optional fp32 out) ----
template<bool ALSO_F32>
__global__ void ln_kernel(const float* __restrict__ x, const float* __restrict__ w,
                          const float* __restrict__ bia, u16* __restrict__ yb,
                          float* __restrict__ yf){
  int row = blockIdx.x;
  const float* xr = x + (size_t)row * IND;
  int t = threadIdx.x;
  float v[3];
  v[0] = xr[t]; v[1] = xr[t+256]; v[2] = xr[t+512];
  float s  = v[0]+v[1]+v[2];
  float sq = v[0]*v[0]+v[1]*v[1]+v[2]*v[2];
  #pragma unroll
  for(int o=1;o<64;o<<=1){ s += __shfl_xor(s, o, 64); sq += __shfl_xor(sq, o, 64); }
  __shared__ float ss[4], ssq[4];
  int wid = t >> 6;
  if((t&63)==0){ ss[wid]=s; ssq[wid]=sq; }
  __syncthreads();
  s  = ss[0]+ss[1]+ss[2]+ss[3];
  sq = ssq[0]+ssq[1]+ssq[2]+ssq[3];
  float mean = s * (1.0f/IND);
  float var  = sq * (1.0f/IND) - mean*mean;
  float rs   = rsqrtf(var + 1e-5f);
  #pragma unroll
  for(int i=0;i<3;i++){
    int idx = t + i*256;
    float y = (v[i]-mean)*rs*w[idx] + bia[idx];
    yb[(size_t)row*IND + idx] = f2b(y);
    if(ALSO_F32) yf[(size_t)row*IND + idx] = y;
  }
}

// ---- NT GEMM: C(rows x N) = A(rows x K) @ Wt(N x K)^T, bf16 MFMA 16x16x32 ----
// R5-proven schedule (best measured): 3-deep ring, stage t+3 while computing
// t, 2 barriers/step, counted vmcnt never drained mid-loop. R6/R7 A/B showed
// 1-barrier and depth-4 variants are neutral-to-worse; do not re-tune.
// OUTM: 0 = bf16 store, 1 = fp32 store, 2 = fp32 += (single writer),
//       3 = bf16 store scaled by 0.125 (softmax d^-0.5 folded into Q)
// GELU uses tanh-form approx (x*sigmoid(1.5958x+0.07135x^3)): exact erff was
// ~64x25 VALU instrs per thread in the up-proj epilogue (~same cost as the
// whole MFMA main loop); approx error <=0.003, absmax headroom 0.016 vs 0.1.
template<int TN, int OUTM, bool BIAS, bool GELU_>
__global__ __launch_bounds__(256) void gemm_bt(const u16* __restrict__ A,
    const u16* __restrict__ Wt, const float* __restrict__ bias,
    void* __restrict__ C, int K, int N){
  constexpr int JT = TN / 32;                 // b-tiles per wave (4 or 2)
  __shared__ __align__(16) u16 As[3][128][32];
  __shared__ __align__(16) u16 Bs[3][TN][32];
  int rowblk = blockIdx.x * 128, colblk = blockIdx.y * TN;
  int tid = threadIdx.x;
  int lane = tid & 63, wv = tid >> 6;
  int wm = (wv >> 1) * 64, wn = (wv & 1) * (16*JT);
  int l16 = lane & 15, quad = lane >> 4;
  f32x4 acc[4][JT] = {};
  int sr = lane >> 2;
  int sc = (((lane & 3) ^ ((lane >> 3) & 3)) * 8);   // staged chunk (XOR swizzle)
  int rc = ((quad ^ ((l16 >> 1) & 3)) * 8);          // read-back column
  const u16* Ap = A  + (size_t)(rowblk + wv*16 + sr) * K + sc;
  const u16* Bp = Wt + (size_t)(colblk + wv*16 + sr) * K + sc;

  auto stage = [&](int step, int bi){
    int kt = step * 32;
    gl_lds16(Ap + kt,                 &As[bi][wv*16][0]);
    gl_lds16(Ap + (size_t)64*K + kt,  &As[bi][64 + wv*16][0]);
    gl_lds16(Bp + kt,                 &Bs[bi][wv*16][0]);
    if constexpr (TN == 128)
      gl_lds16(Bp + (size_t)64*K + kt, &Bs[bi][64 + wv*16][0]);
  };
  auto compute = [&](int bi){
    bf16x8 af[4], bfr[JT];
    #pragma unroll
    for(int i=0;i<4;i++)  af[i]  = *(const bf16x8*)&As[bi][wm + i*16 + l16][rc];
    #pragma unroll
    for(int j=0;j<JT;j++) bfr[j] = *(const bf16x8*)&Bs[bi][wn + j*16 + l16][rc];
    #pragma unroll
    for(int i=0;i<4;i++)
      #pragma unroll
      for(int j=0;j<JT;j++)
        acc[i][j] = __builtin_amdgcn_mfma_f32_16x16x32_bf16(af[i], bfr[j], acc[i][j], 0, 0, 0);
  };

  int nt = K / 32;            // 12 / 24 / 96 for our shapes, always >= 3
  stage(0, 0); stage(1, 1); stage(2, 2);

  int bi = 0;
  for(int t = 0; t < nt - 3; ++t){
    // wait for oldest staged step only; 2 steps stay in flight
    if constexpr (TN == 128) asm volatile("s_waitcnt vmcnt(8)" ::: "memory");
    else                     asm volatile("s_waitcnt vmcnt(6)" ::: "memory");
    __builtin_amdgcn_s_barrier();
    __builtin_amdgcn_sched_barrier(0);
    compute(bi);
    __builtin_amdgcn_sched_barrier(0);
    asm volatile("" ::: "memory");
    __builtin_amdgcn_s_barrier();          // all reads of buf bi done
    stage(t + 3, bi);                      // overwrite it with step t+3
    bi = (bi == 2) ? 0 : bi + 1;
  }
  // tail: 3 remaining computes, draining the pipeline
  if constexpr (TN == 128) asm volatile("s_waitcnt vmcnt(8)" ::: "memory");
  else                     asm volatile("s_waitcnt vmcnt(6)" ::: "memory");
  __builtin_amdgcn_s_barrier();
  __builtin_amdgcn_sched_barrier(0);
  compute(bi); bi = (bi == 2) ? 0 : bi + 1;

  if constexpr (TN == 128) asm volatile("s_waitcnt vmcnt(4)" ::: "memory");
  else                     asm volatile("s_waitcnt vmcnt(3)" ::: "memory");
  __builtin_amdgcn_s_barrier();
  __builtin_amdgcn_sched_barrier(0);
  compute(bi); bi = (bi == 2) ? 0 : bi + 1;

  asm volatile("s_waitcnt vmcnt(0)" ::: "memory");
  __builtin_amdgcn_s_barrier();
  __builtin_amdgcn_sched_barrier(0);
  compute(bi);

  #pragma unroll
  for(int i=0;i<4;i++){
    #pragma unroll
    for(int j=0;j<JT;j++){
      int grow = rowblk + wm + i*16 + quad*4;
      int gcol = colblk + wn + j*16 + l16;
      float bv = BIAS ? bias[gcol] : 0.0f;
      #pragma unroll
      for(int rg=0; rg<4; rg++){
        float vval = acc[i][j][rg] + bv;
        if(GELU_){
          // gelu(x) ~= x * sigmoid(1.595769x + 0.0713548x^3)  (tanh form)
          float y = vval * (1.595769122f + 0.071354816f * vval * vval);
          vval = vval / (1.0f + __expf(-y));
        }
        size_t idx = (size_t)(grow + rg) * N + gcol;
        if(OUTM == 0)      ((u16*)C)[idx]   = f2b(vval);
        else if(OUTM == 3) ((u16*)C)[idx]   = f2b(vval * 0.125f);
        else if(OUTM == 1) ((float*)C)[idx] = vval;
        else               ((float*)C)[idx] += vval;
      }
    }
  }
}

// ---- flash attention v6 ----
// R5-proven synchronous global->LDS staging + VALU cuts (QK via 16x16x32,
// Q pre-scaled, __expf, f2b P-pack). New: s_setprio(1) around MFMA clusters
// (T5) -- blocks on a CU run at independent phases here, so priority lets
// MFMA-phase waves preempt staging waves.
__global__ __launch_bounds__(256) void attn_kernel(const u16* __restrict__ Q,
    const u16* __restrict__ KV, const u16* __restrict__ Vtg,
    u16* __restrict__ AO, int M){
  __shared__ __align__(16) u16 Ks[128][72];   // [ctx][d]  144B stride (16B-aligned)
  __shared__ __align__(16) u16 Vs[64][132];   // [d][ctx]  +4 pad
  int tid = threadIdx.x, lane = tid & 63, wv = tid >> 6;
  int bh = blockIdx.x % (B_*NH);              // XCD = bh % 8 for all its q-tiles
  int qt = blockIdx.x / (B_*NH);
  int h = bh % NH, b = bh / NH;
  int l16 = lane & 15, quad = lane >> 4;

  // Q fragment for 16x16x32: lane (l16,quad) holds d = s*32 + quad*8 .. +7
  bf16x8 qf[2];
  const u16* qp = Q + (size_t)(b*NQ + qt*64 + wv*16 + l16) * DIM + h*HD + quad*8;
  qf[0] = *(const bf16x8*)(qp);
  qf[1] = *(const bf16x8*)(qp + 32);

  f32x4 o[4] = {};
  float lacc = 0.f;

  for(int cb = 0; cb < M; cb += 128){
    __syncthreads();
    #pragma unroll
    for(int it=0; it<4; it++){
      int idx = tid + it*256;
      int row = idx >> 3, c8 = (idx & 7) * 8;
      *(int4*)&Ks[row][c8] =
        *(const int4*)(KV + (size_t)(b*M + cb + row)*(2*DIM) + h*HD + c8);
    }
    #pragma unroll
    for(int it=0; it<4; it++){
      int idx = tid + it*256;
      int dd = idx >> 4, c8 = (idx & 15) * 8;
      *(int4*)&Vs[dd][c8] =
        *(const int4*)(Vtg + (size_t)(bh*HD + dd)*M + cb + c8);
    }
    __syncthreads();

    s16x4 pp[8];
    #pragma unroll
    for(int cc=0; cc<8; cc++){
      f32x4 z = {};
      __builtin_amdgcn_s_setprio(1);
      #pragma unroll
      for(int s=0;s<2;s++){
        bf16x8 kf = *(const bf16x8*)&Ks[cc*16 + l16][quad*8 + s*32];
        z = __builtin_amdgcn_mfma_f32_16x16x32_bf16(kf, qf[s], z, 0,0,0);
      }
      __builtin_amdgcn_s_setprio(0);
      float p0 = __expf(z[0]), p1 = __expf(z[1]);
      float p2 = __expf(z[2]), p3 = __expf(z[3]);
      lacc += (p0+p1) + (p2+p3);
      s16x4 pb;
      pb[0] = (short)f2b(p0); pb[1] = (short)f2b(p1);
      pb[2] = (short)f2b(p2); pb[3] = (short)f2b(p3);
      pp[cc] = pb;
    }
    __builtin_amdgcn_s_setprio(1);
    #pragma unroll
    for(int dn=0;dn<4;dn++){
      #pragma unroll
      for(int tt=0;tt<8;tt++){
        s16x4 vf = *(const s16x4*)&Vs[dn*16 + l16][quad*4 + tt*16];
        o[dn] = __builtin_amdgcn_mfma_f32_16x16x16bf16_1k(vf, pp[tt], o[dn], 0,0,0);
      }
    }
    __builtin_amdgcn_s_setprio(0);
  }

  lacc += __shfl_xor(lacc, 16, 64);
  lacc += __shfl_xor(lacc, 32, 64);
  float rl = 1.0f / lacc;

  u16* aop = AO + (size_t)(b*NQ + qt*64 + wv*16 + l16) * DIM + h*HD + quad*4;
  #pragma unroll
  for(int dn=0;dn<4;dn++){
    s16x4 ob;
    #pragma unroll
    for(int r=0;r<4;r++) ob[r] = (short)f2b(o[dn][r] * rl);
    *(s16x4*)(aop + dn*16) = ob;
  }
}

extern "C" void kernel_launch(void* const* d_in, const int* in_sizes, int n_in,
                              void* d_out, int out_size, void* d_ws, size_t ws_size,
                              hipStream_t stream){
  const float* query   = (const float*)d_in[0];
  const float* context = (const float*)d_in[1];
  const float* ln_w  = (const float*)d_in[2];
  const float* ln_b  = (const float*)d_in[3];
  const float* a1_wq = (const float*)d_in[4];
  const float* a1_wkv= (const float*)d_in[5];
  const float* a1_wp = (const float*)d_in[6];
  const float* a1_bp = (const float*)d_in[7];
  const float* m1_w1 = (const float*)d_in[8];
  const float* m1_b1 = (const float*)d_in[9];
  const float* m1_w2 = (const float*)d_in[10];
  const float* m1_b2 = (const float*)d_in[11];
  const float* a2_wq = (const float*)d_in[12];
  const float* a2_wkv= (const float*)d_in[13];
  const float* a2_wp = (const float*)d_in[14];
  const float* a2_bp = (const float*)d_in[15];
  const float* m2_w1 = (const float*)d_in[16];
  const float* m2_b1 = (const float*)d_in[17];
  const float* m2_w2 = (const float*)d_in[18];
  const float* m2_b2 = (const float*)d_in[19];
  (void)in_sizes; (void)n_in; (void)out_size; (void)ws_size;

  float* c_out = (float*)d_out;                    // output 0: c (8,1024,768) fp32
  float* q_out = c_out + (size_t)B_*NQ*IND;        // output 1: q (8,1024,768) fp32

  char* base = (char*)d_ws;
  size_t off = 0;
  auto alloc = [&](size_t elems)->u16*{
    u16* p = (u16*)(base + off);
    off += ((elems*2) + 255) & ~(size_t)255;
    return p;
  };
  u16* wq1t  = alloc((size_t)DIM*IND);
  u16* wkv1t = alloc((size_t)2*DIM*IND);
  u16* wp1t  = alloc((size_t)IND*DIM);
  u16* w11t  = alloc((size_t)HID*IND);
  u16* w21t  = alloc((size_t)IND*HID);
  u16* wq2t  = alloc((size_t)DIM*IND);
  u16* wkv2t = alloc((size_t)2*DIM*IND);
  u16* wp2t  = alloc((size_t)IND*DIM);
  u16* w12t  = alloc((size_t)HID*IND);
  u16* w22t  = alloc((size_t)IND*HID);
  u16* qn_b  = alloc((size_t)B_*NQ*IND);
  u16* cn_b  = alloc((size_t)B_*NC*IND);
  u16* Tb    = alloc((size_t)B_*NQ*IND);
  u16* Qb    = alloc((size_t)B_*NQ*DIM);
  u16* KVb   = alloc((size_t)B_*NC*2*DIM);
  u16* AOb   = alloc((size_t)B_*NQ*DIM);
  u16* Hb    = alloc((size_t)B_*NQ*HID);
  u16* Vtb   = Hb;   // alias: Hb idle during attention phases

  dim3 tb(32,8);
  wtrans_kernel<<<dim3(DIM/32,   IND/32), tb, 0, stream>>>(a1_wq,  wq1t,  IND, DIM);
  wtrans_kernel<<<dim3(2*DIM/32, IND/32), tb, 0, stream>>>(a1_wkv, wkv1t, IND, 2*DIM);
  wtrans_kernel<<<dim3(IND/32,   DIM/32), tb, 0, stream>>>(a1_wp,  wp1t,  DIM, IND);
  wtrans_kernel<<<dim3(HID/32,   IND/32), tb, 0, stream>>>(m1_w1,  w11t,  IND, HID);
  wtrans_kernel<<<dim3(IND/32,   HID/32), tb, 0, stream>>>(m1_w2,  w21t,  HID, IND);
  wtrans_kernel<<<dim3(DIM/32,   IND/32), tb, 0, stream>>>(a2_wq,  wq2t,  IND, DIM);
  wtrans_kernel<<<dim3(2*DIM/32, IND/32), tb, 0, stream>>>(a2_wkv, wkv2t, IND, 2*DIM);
  wtrans_kernel<<<dim3(IND/32,   DIM/32), tb, 0, stream>>>(a2_wp,  wp2t,  DIM, IND);
  wtrans_kernel<<<dim3(HID/32,   IND/32), tb, 0, stream>>>(m2_w1,  w12t,  IND, HID);
  wtrans_kernel<<<dim3(IND/32,   HID/32), tb, 0, stream>>>(m2_w2,  w22t,  HID, IND);

  ln_kernel<true ><<<B_*NQ, 256, 0, stream>>>(query,   ln_w, ln_b, qn_b, q_out);
  ln_kernel<false><<<B_*NC, 256, 0, stream>>>(context, ln_w, ln_b, cn_b, nullptr);

  // --- block 1: cross-attention ---
  gemm_bt<64,3,false,false><<<dim3(B_*NQ/128, DIM/64),  256, 0, stream>>>(qn_b, wq1t,  nullptr, Qb,  IND, DIM);
  gemm_bt<128,0,false,false><<<dim3(B_*NC/128, 2*DIM/128), 256, 0, stream>>>(cn_b, wkv1t, nullptr, KVb, IND, 2*DIM);
  vtrans_kernel<<<dim3(NC/64, B_*NH), 256, 0, stream>>>(KVb, Vtb, NC);
  attn_kernel<<<B_*NH*(NQ/64), 256, 0, stream>>>(Qb, KVb, Vtb, AOb, NC);
  gemm_bt<64,1,true,false><<<dim3(B_*NQ/128, IND/64), 256, 0, stream>>>(AOb, wp1t, a1_bp, c_out, DIM, IND);
  // --- MLP 1 ---
  ln_kernel<false><<<B_*NQ, 256, 0, stream>>>(c_out, ln_w, ln_b, Tb, nullptr);
  gemm_bt<128,0,true,true ><<<dim3(B_*NQ/128, HID/128), 256, 0, stream>>>(Tb, w11t, m1_b1, Hb, IND, HID);
  gemm_bt<64,2,true,false><<<dim3(B_*NQ/128, IND/64), 256, 0, stream>>>(Hb, w21t, m1_b2, c_out, HID, IND);
  // --- block 2: cross-attention (q reused, kv from LN(c)) ---
  ln_kernel<false><<<B_*NQ, 256, 0, stream>>>(c_out, ln_w, ln_b, Tb, nullptr);
  gemm_bt<64,3,false,false><<<dim3(B_*NQ/128, DIM/64),  256, 0, stream>>>(qn_b, wq2t,  nullptr, Qb,  IND, DIM);
  gemm_bt<64,0,false,false><<<dim3(B_*NQ/128, 2*DIM/64), 256, 0, stream>>>(Tb,   wkv2t, nullptr, KVb, IND, 2*DIM);
  vtrans_kernel<<<dim3(NQ/64, B_*NH), 256, 0, stream>>>(KVb, Vtb, NQ);
  attn_kernel<<<B_*NH*(NQ/64), 256, 0, stream>>>(Qb, KVb, Vtb, AOb, NQ);
  gemm_bt<64,2,true,false><<<dim3(B_*NQ/128, IND/64), 256, 0, stream>>>(AOb, wp2t, a2_bp, c_out, DIM, IND);
  // --- MLP 2 ---
  ln_kernel<false><<<B_*NQ, 256, 0, stream>>>(c_out, ln_w, ln_b, Tb, nullptr);
  gemm_bt<128,0,true,true ><<<dim3(B_*NQ/128, HID/128), 256, 0, stream>>>(Tb, w12t, m2_b1, Hb, IND, HID);
  gemm_bt<64,2,true,false><<<dim3(B_*NQ/128, IND/64), 256, 0, stream>>>(Hb, w22t, m2_b2, c_out, HID, IND);
}

// Round 9
// 689.103 us; speedup vs baseline: 1.0736x; 1.0011x over previous
//
#include <hip/hip_runtime.h>
#include <hip/hip_bf16.h>
#include <math.h>

typedef unsigned short u16;
typedef __bf16 bf16x8 __attribute__((ext_vector_type(8)));
typedef short s16x4 __attribute__((ext_vector_type(4)));
typedef float f32x4 __attribute__((ext_vector_type(4)));

#define B_   8
#define NQ   1024
#define NC   2048
#define IND  768
#define DIM  384
#define NH   6
#define HD   64
#define HID  3072

__device__ __forceinline__ u16 f2b(float f){
  unsigned int x = __float_as_uint(f);
  return (u16)((x + 0x7fffu + ((x >> 16) & 1u)) >> 16);
}

__device__ __forceinline__ void gl_lds16(const u16* g, u16* l){
  __builtin_amdgcn_global_load_lds(
    (const __attribute__((address_space(1))) unsigned int*)g,
    (__attribute__((address_space(3))) unsigned int*)l, 16, 0, 0);
}

// ---- weight convert+transpose: W (K x N) fp32 -> Wt (N x K) bf16 ----
__global__ void wtrans_kernel(const float* __restrict__ W, u16* __restrict__ Wt,
                              int K, int N){
  __shared__ float tile[32][33];
  int n0 = blockIdx.x * 32, k0 = blockIdx.y * 32;
  int tx = threadIdx.x, ty = threadIdx.y;   // 32 x 8
  #pragma unroll
  for(int i=0;i<4;i++) tile[ty*4+i][tx] = W[(size_t)(k0+ty*4+i)*N + n0 + tx];
  __syncthreads();
  #pragma unroll
  for(int i=0;i<4;i++) Wt[(size_t)(n0+ty*4+i)*K + k0 + tx] = f2b(tile[tx][ty*4+i]);
}

// ---- V transpose: KV (b, m, 2, h, d) -> Vt (b, h, d, m) bf16 ----
__global__ void vtrans_kernel(const u16* __restrict__ KV, u16* __restrict__ Vt, int M){
  __shared__ u16 t[64][72];
  int bh = blockIdx.y; int b = bh / NH, h = bh % NH;
  int m0 = blockIdx.x * 64;
  int tx = threadIdx.x & 63, ty = threadIdx.x >> 6;   // 64 x 4
  #pragma unroll
  for(int i=0;i<16;i++){
    int mm = ty*16+i;
    t[mm][tx] = KV[(size_t)(b*M + m0 + mm)*(2*DIM) + DIM + h*HD + tx];
  }
  __syncthreads();
  #pragma unroll
  for(int i=0;i<16;i++){
    int dd = ty*16+i;
    Vt[(size_t)(bh*HD + dd)*M + m0 + tx] = t[tx][dd];
  }
}

// ---- layernorm over rows of 768: fp32 in -> bf16 out (+optional fp32 out) ----
template<bool ALSO_F32>
__global__ void ln_kernel(const float* __restrict__ x, const float* __restrict__ w,
                          const float* __restrict__ bia, u16* __restrict__ yb,
                          float* __restrict__ yf){
  int row = blockIdx.x;
  const float* xr = x + (size_t)row * IND;
  int t = threadIdx.x;
  float v[3];
  v[0] = xr[t]; v[1] = xr[t+256]; v[2] = xr[t+512];
  float s  = v[0]+v[1]+v[2];
  float sq = v[0]*v[0]+v[1]*v[1]+v[2]*v[2];
  #pragma unroll
  for(int o=1;o<64;o<<=1){ s += __shfl_xor(s, o, 64); sq += __shfl_xor(sq, o, 64); }
  __shared__ float ss[4], ssq[4];
  int wid = t >> 6;
  if((t&63)==0){ ss[wid]=s; ssq[wid]=sq; }
  __syncthreads();
  s  = ss[0]+ss[1]+ss[2]+ss[3];
  sq = ssq[0]+ssq[1]+ssq[2]+ssq[3];
  float mean = s * (1.0f/IND);
  float var  = sq * (1.0f/IND) - mean*mean;
  float rs   = rsqrtf(var + 1e-5f);
  #pragma unroll
  for(int i=0;i<3;i++){
    int idx = t + i*256;
    float y = (v[i]-mean)*rs*w[idx] + bia[idx];
    yb[(size_t)row*IND + idx] = f2b(y);
    if(ALSO_F32) yf[(size_t)row*IND + idx] = y;
  }
}

// ---- NT GEMM: C(rows x N) = A(rows x K) @ Wt(N x K)^T, bf16 MFMA 16x16x32 ----
// BKH=1 (default): R5-proven schedule -- 3-deep ring, BK=32, stage t+3 while
// computing t, 2 barriers/step, counted vmcnt. R6/R7 showed 1-barrier and
// depth variants at BK=32 are neutral-to-worse; do not re-tune.
// BKH=2 (K large, e.g. MLP down-proj K=3072): BK=64 halves the step count --
// per-step fixed cost (2 rendezvous + lgkm drain, ~40% of step time at BK=32)
// amortizes over 2x the work. Depth-2/2-buffer, ONE barrier/step (one step
// now spans ~2600cyc > ~900cyc HBM latency, so 1-step lookahead suffices).
// LDS 48KB -> still 3 blocks/CU. Two stacked 32-col panels per buffer keep
// the gl_lds linear-write + XOR chunk swizzle layout intact.
// OUTM: 0 = bf16 store, 1 = fp32 store, 2 = fp32 += (single writer),
//       3 = bf16 store scaled by 0.125 (softmax d^-0.5 folded into Q)
// GELU uses tanh-form approx (x*sigmoid(1.5958x+0.07135x^3)): exact erff was
// ~64x25 VALU instrs per thread in the up-proj epilogue; approx error
// <=0.003, absmax headroom 0.016 vs 0.1 (R8: absmax 0.0161, passed).
template<int TN, int OUTM, bool BIAS, bool GELU_, int BKH = 1>
__global__ __launch_bounds__(256) void gemm_bt(const u16* __restrict__ A,
    const u16* __restrict__ Wt, const float* __restrict__ bias,
    void* __restrict__ C, int K, int N){
  constexpr int JT = TN / 32;                 // b-tiles per wave (4 or 2)
  constexpr int DEPTH = (BKH == 2) ? 2 : 3;
  __shared__ __align__(16) u16 As[DEPTH][BKH][128][32];
  __shared__ __align__(16) u16 Bs[DEPTH][BKH][TN][32];
  int rowblk = blockIdx.x * 128, colblk = blockIdx.y * TN;
  int tid = threadIdx.x;
  int lane = tid & 63, wv = tid >> 6;
  int wm = (wv >> 1) * 64, wn = (wv & 1) * (16*JT);
  int l16 = lane & 15, quad = lane >> 4;
  f32x4 acc[4][JT] = {};
  int sr = lane >> 2;
  int sc = (((lane & 3) ^ ((lane >> 3) & 3)) * 8);   // staged chunk (XOR swizzle)
  int rc = ((quad ^ ((l16 >> 1) & 3)) * 8);          // read-back column
  const u16* Ap = A  + (size_t)(rowblk + wv*16 + sr) * K + sc;
  const u16* Bp = Wt + (size_t)(colblk + wv*16 + sr) * K + sc;

  auto stage = [&](int step, int bi){
    #pragma unroll
    for(int h=0; h<BKH; h++){
      int kt = step * (32*BKH) + h*32;
      gl_lds16(Ap + kt,                 &As[bi][h][wv*16][0]);
      gl_lds16(Ap + (size_t)64*K + kt,  &As[bi][h][64 + wv*16][0]);
      gl_lds16(Bp + kt,                 &Bs[bi][h][wv*16][0]);
      if constexpr (TN == 128)
        gl_lds16(Bp + (size_t)64*K + kt, &Bs[bi][h][64 + wv*16][0]);
    }
  };
  auto compute = [&](int bi){
    #pragma unroll
    for(int h=0; h<BKH; h++){
      bf16x8 af[4], bfr[JT];
      #pragma unroll
      for(int i=0;i<4;i++)  af[i]  = *(const bf16x8*)&As[bi][h][wm + i*16 + l16][rc];
      #pragma unroll
      for(int j=0;j<JT;j++) bfr[j] = *(const bf16x8*)&Bs[bi][h][wn + j*16 + l16][rc];
      #pragma unroll
      for(int i=0;i<4;i++)
        #pragma unroll
        for(int j=0;j<JT;j++)
          acc[i][j] = __builtin_amdgcn_mfma_f32_16x16x32_bf16(af[i], bfr[j], acc[i][j], 0, 0, 0);
    }
  };

  if constexpr (BKH == 2){
    // ---- BK=64, depth-2, one barrier per step ----
    int nt = K / 64;
    stage(0, 0);
    int bi = 0;
    for(int t = 0; t < nt - 1; ++t){
      asm volatile("s_waitcnt vmcnt(0)" ::: "memory");   // stage(t) landed
      __builtin_amdgcn_s_barrier();                      // buf bi^1 reads done
      __builtin_amdgcn_sched_barrier(0);
      stage(t + 1, bi ^ 1);                              // issue early
      __builtin_amdgcn_sched_barrier(0);
      compute(bi);
      bi ^= 1;
    }
    asm volatile("s_waitcnt vmcnt(0)" ::: "memory");
    __builtin_amdgcn_s_barrier();
    __builtin_amdgcn_sched_barrier(0);
    compute(bi);
  } else {
    // ---- R5 schedule: BK=32, 3-deep ring, 2 barriers per step ----
    int nt = K / 32;
    stage(0, 0); stage(1, 1); stage(2, 2);
    int bi = 0;
    for(int t = 0; t < nt - 3; ++t){
      if constexpr (TN == 128) asm volatile("s_waitcnt vmcnt(8)" ::: "memory");
      else                     asm volatile("s_waitcnt vmcnt(6)" ::: "memory");
      __builtin_amdgcn_s_barrier();
      __builtin_amdgcn_sched_barrier(0);
      compute(bi);
      __builtin_amdgcn_sched_barrier(0);
      asm volatile("" ::: "memory");
      __builtin_amdgcn_s_barrier();          // all reads of buf bi done
      stage(t + 3, bi);                      // overwrite it with step t+3
      bi = (bi == 2) ? 0 : bi + 1;
    }
    if constexpr (TN == 128) asm volatile("s_waitcnt vmcnt(8)" ::: "memory");
    else                     asm volatile("s_waitcnt vmcnt(6)" ::: "memory");
    __builtin_amdgcn_s_barrier();
    __builtin_amdgcn_sched_barrier(0);
    compute(bi); bi = (bi == 2) ? 0 : bi + 1;

    if constexpr (TN == 128) asm volatile("s_waitcnt vmcnt(4)" ::: "memory");
    else                     asm volatile("s_waitcnt vmcnt(3)" ::: "memory");
    __builtin_amdgcn_s_barrier();
    __builtin_amdgcn_sched_barrier(0);
    compute(bi); bi = (bi == 2) ? 0 : bi + 1;

    asm volatile("s_waitcnt vmcnt(0)" ::: "memory");
    __builtin_amdgcn_s_barrier();
    __builtin_amdgcn_sched_barrier(0);
    compute(bi);
  }

  #pragma unroll
  for(int i=0;i<4;i++){
    #pragma unroll
    for(int j=0;j<JT;j++){
      int grow = rowblk + wm + i*16 + quad*4;
      int gcol = colblk + wn + j*16 + l16;
      float bv = BIAS ? bias[gcol] : 0.0f;
      #pragma unroll
      for(int rg=0; rg<4; rg++){
        float vval = acc[i][j][rg] + bv;
        if(GELU_){
          // gelu(x) ~= x * sigmoid(1.595769x + 0.0713548x^3)  (tanh form)
          float y = vval * (1.595769122f + 0.071354816f * vval * vval);
          vval = vval / (1.0f + __expf(-y));
        }
        size_t idx = (size_t)(grow + rg) * N + gcol;
        if(OUTM == 0)      ((u16*)C)[idx]   = f2b(vval);
        else if(OUTM == 3) ((u16*)C)[idx]   = f2b(vval * 0.125f);
        else if(OUTM == 1) ((float*)C)[idx] = vval;
        else               ((float*)C)[idx] += vval;
      }
    }
  }
}

// ---- flash attention v6 ----
// R5-proven synchronous global->LDS staging + VALU cuts (QK via 16x16x32,
// Q pre-scaled, __expf, f2b P-pack) + s_setprio(1) around MFMA clusters (T5).
__global__ __launch_bounds__(256) void attn_kernel(const u16* __restrict__ Q,
    const u16* __restrict__ KV, const u16* __restrict__ Vtg,
    u16* __restrict__ AO, int M){
  __shared__ __align__(16) u16 Ks[128][72];   // [ctx][d]  144B stride (16B-aligned)
  __shared__ __align__(16) u16 Vs[64][132];   // [d][ctx]  +4 pad
  int tid = threadIdx.x, lane = tid & 63, wv = tid >> 6;
  int bh = blockIdx.x % (B_*NH);              // XCD = bh % 8 for all its q-tiles
  int qt = blockIdx.x / (B_*NH);
  int h = bh % NH, b = bh / NH;
  int l16 = lane & 15, quad = lane >> 4;

  // Q fragment for 16x16x32: lane (l16,quad) holds d = s*32 + quad*8 .. +7
  bf16x8 qf[2];
  const u16* qp = Q + (size_t)(b*NQ + qt*64 + wv*16 + l16) * DIM + h*HD + quad*8;
  qf[0] = *(const bf16x8*)(qp);
  qf[1] = *(const bf16x8*)(qp + 32);

  f32x4 o[4] = {};
  float lacc = 0.f;

  for(int cb = 0; cb < M; cb += 128){
    __syncthreads();
    #pragma unroll
    for(int it=0; it<4; it++){
      int idx = tid + it*256;
      int row = idx >> 3, c8 = (idx & 7) * 8;
      *(int4*)&Ks[row][c8] =
        *(const int4*)(KV + (size_t)(b*M + cb + row)*(2*DIM) + h*HD + c8);
    }
    #pragma unroll
    for(int it=0; it<4; it++){
      int idx = tid + it*256;
      int dd = idx >> 4, c8 = (idx & 15) * 8;
      *(int4*)&Vs[dd][c8] =
        *(const int4*)(Vtg + (size_t)(bh*HD + dd)*M + cb + c8);
    }
    __syncthreads();

    s16x4 pp[8];
    #pragma unroll
    for(int cc=0; cc<8; cc++){
      f32x4 z = {};
      __builtin_amdgcn_s_setprio(1);
      #pragma unroll
      for(int s=0;s<2;s++){
        bf16x8 kf = *(const bf16x8*)&Ks[cc*16 + l16][quad*8 + s*32];
        z = __builtin_amdgcn_mfma_f32_16x16x32_bf16(kf, qf[s], z, 0,0,0);
      }
      __builtin_amdgcn_s_setprio(0);
      float p0 = __expf(z[0]), p1 = __expf(z[1]);
      float p2 = __expf(z[2]), p3 = __expf(z[3]);
      lacc += (p0+p1) + (p2+p3);
      s16x4 pb;
      pb[0] = (short)f2b(p0); pb[1] = (short)f2b(p1);
      pb[2] = (short)f2b(p2); pb[3] = (short)f2b(p3);
      pp[cc] = pb;
    }
    __builtin_amdgcn_s_setprio(1);
    #pragma unroll
    for(int dn=0;dn<4;dn++){
      #pragma unroll
      for(int tt=0;tt<8;tt++){
        s16x4 vf = *(const s16x4*)&Vs[dn*16 + l16][quad*4 + tt*16];
        o[dn] = __builtin_amdgcn_mfma_f32_16x16x16bf16_1k(vf, pp[tt], o[dn], 0,0,0);
      }
    }
    __builtin_amdgcn_s_setprio(0);
  }

  lacc += __shfl_xor(lacc, 16, 64);
  lacc += __shfl_xor(lacc, 32, 64);
  float rl = 1.0f / lacc;

  u16* aop = AO + (size_t)(b*NQ + qt*64 + wv*16 + l16) * DIM + h*HD + quad*4;
  #pragma unroll
  for(int dn=0;dn<4;dn++){
    s16x4 ob;
    #pragma unroll
    for(int r=0;r<4;r++) ob[r] = (short)f2b(o[dn][r] * rl);
    *(s16x4*)(aop + dn*16) = ob;
  }
}

extern "C" void kernel_launch(void* const* d_in, const int* in_sizes, int n_in,
                              void* d_out, int out_size, void* d_ws, size_t ws_size,
                              hipStream_t stream){
  const float* query   = (const float*)d_in[0];
  const float* context = (const float*)d_in[1];
  const float* ln_w  = (const float*)d_in[2];
  const float* ln_b  = (const float*)d_in[3];
  const float* a1_wq = (const float*)d_in[4];
  const float* a1_wkv= (const float*)d_in[5];
  const float* a1_wp = (const float*)d_in[6];
  const float* a1_bp = (const float*)d_in[7];
  const float* m1_w1 = (const float*)d_in[8];
  const float* m1_b1 = (const float*)d_in[9];
  const float* m1_w2 = (const float*)d_in[10];
  const float* m1_b2 = (const float*)d_in[11];
  const float* a2_wq = (const float*)d_in[12];
  const float* a2_wkv= (const float*)d_in[13];
  const float* a2_wp = (const float*)d_in[14];
  const float* a2_bp = (const float*)d_in[15];
  const float* m2_w1 = (const float*)d_in[16];
  const float* m2_b1 = (const float*)d_in[17];
  const float* m2_w2 = (const float*)d_in[18];
  const float* m2_b2 = (const float*)d_in[19];
  (void)in_sizes; (void)n_in; (void)out_size; (void)ws_size;

  float* c_out = (float*)d_out;                    // output 0: c (8,1024,768) fp32
  float* q_out = c_out + (size_t)B_*NQ*IND;        // output 1: q (8,1024,768) fp32

  char* base = (char*)d_ws;
  size_t off = 0;
  auto alloc = [&](size_t elems)->u16*{
    u16* p = (u16*)(base + off);
    off += ((elems*2) + 255) & ~(size_t)255;
    return p;
  };
  u16* wq1t  = alloc((size_t)DIM*IND);
  u16* wkv1t = alloc((size_t)2*DIM*IND);
  u16* wp1t  = alloc((size_t)IND*DIM);
  u16* w11t  = alloc((size_t)HID*IND);
  u16* w21t  = alloc((size_t)IND*HID);
  u16* wq2t  = alloc((size_t)DIM*IND);
  u16* wkv2t = alloc((size_t)2*DIM*IND);
  u16* wp2t  = alloc((size_t)IND*DIM);
  u16* w12t  = alloc((size_t)HID*IND);
  u16* w22t  = alloc((size_t)IND*HID);
  u16* qn_b  = alloc((size_t)B_*NQ*IND);
  u16* cn_b  = alloc((size_t)B_*NC*IND);
  u16* Tb    = alloc((size_t)B_*NQ*IND);
  u16* Qb    = alloc((size_t)B_*NQ*DIM);
  u16* KVb   = alloc((size_t)B_*NC*2*DIM);
  u16* AOb   = alloc((size_t)B_*NQ*DIM);
  u16* Hb    = alloc((size_t)B_*NQ*HID);
  u16* Vtb   = Hb;   // alias: Hb idle during attention phases

  dim3 tb(32,8);
  wtrans_kernel<<<dim3(DIM/32,   IND/32), tb, 0, stream>>>(a1_wq,  wq1t,  IND, DIM);
  wtrans_kernel<<<dim3(2*DIM/32, IND/32), tb, 0, stream>>>(a1_wkv, wkv1t, IND, 2*DIM);
  wtrans_kernel<<<dim3(IND/32,   DIM/32), tb, 0, stream>>>(a1_wp,  wp1t,  DIM, IND);
  wtrans_kernel<<<dim3(HID/32,   IND/32), tb, 0, stream>>>(m1_w1,  w11t,  IND, HID);
  wtrans_kernel<<<dim3(IND/32,   HID/32), tb, 0, stream>>>(m1_w2,  w21t,  HID, IND);
  wtrans_kernel<<<dim3(DIM/32,   IND/32), tb, 0, stream>>>(a2_wq,  wq2t,  IND, DIM);
  wtrans_kernel<<<dim3(2*DIM/32, IND/32), tb, 0, stream>>>(a2_wkv, wkv2t, IND, 2*DIM);
  wtrans_kernel<<<dim3(IND/32,   DIM/32), tb, 0, stream>>>(a2_wp,  wp2t,  DIM, IND);
  wtrans_kernel<<<dim3(HID/32,   IND/32), tb, 0, stream>>>(m2_w1,  w12t,  IND, HID);
  wtrans_kernel<<<dim3(IND/32,   HID/32), tb, 0, stream>>>(m2_w2,  w22t,  HID, IND);

  ln_kernel<true ><<<B_*NQ, 256, 0, stream>>>(query,   ln_w, ln_b, qn_b, q_out);
  ln_kernel<false><<<B_*NC, 256, 0, stream>>>(context, ln_w, ln_b, cn_b, nullptr);

  // --- block 1: cross-attention ---
  gemm_bt<64,3,false,false><<<dim3(B_*NQ/128, DIM/64),  256, 0, stream>>>(qn_b, wq1t,  nullptr, Qb,  IND, DIM);
  gemm_bt<128,0,false,false><<<dim3(B_*NC/128, 2*DIM/128), 256, 0, stream>>>(cn_b, wkv1t, nullptr, KVb, IND, 2*DIM);
  vtrans_kernel<<<dim3(NC/64, B_*NH), 256, 0, stream>>>(KVb, Vtb, NC);
  attn_kernel<<<B_*NH*(NQ/64), 256, 0, stream>>>(Qb, KVb, Vtb, AOb, NC);
  gemm_bt<64,1,true,false><<<dim3(B_*NQ/128, IND/64), 256, 0, stream>>>(AOb, wp1t, a1_bp, c_out, DIM, IND);
  // --- MLP 1 ---
  ln_kernel<false><<<B_*NQ, 256, 0, stream>>>(c_out, ln_w, ln_b, Tb, nullptr);
  gemm_bt<128,0,true,true ><<<dim3(B_*NQ/128, HID/128), 256, 0, stream>>>(Tb, w11t, m1_b1, Hb, IND, HID);
  gemm_bt<64,2,true,false,2><<<dim3(B_*NQ/128, IND/64), 256, 0, stream>>>(Hb, w21t, m1_b2, c_out, HID, IND);
  // --- block 2: cross-attention (q reused, kv from LN(c)) ---
  ln_kernel<false><<<B_*NQ, 256, 0, stream>>>(c_out, ln_w, ln_b, Tb, nullptr);
  gemm_bt<64,3,false,false><<<dim3(B_*NQ/128, DIM/64),  256, 0, stream>>>(qn_b, wq2t,  nullptr, Qb,  IND, DIM);
  gemm_bt<64,0,false,false><<<dim3(B_*NQ/128, 2*DIM/64), 256, 0, stream>>>(Tb,   wkv2t, nullptr, KVb, IND, 2*DIM);
  vtrans_kernel<<<dim3(NQ/64, B_*NH), 256, 0, stream>>>(KVb, Vtb, NQ);
  attn_kernel<<<B_*NH*(NQ/64), 256, 0, stream>>>(Qb, KVb, Vtb, AOb, NQ);
  gemm_bt<64,2,true,false><<<dim3(B_*NQ/128, IND/64), 256, 0, stream>>>(AOb, wp2t, a2_bp, c_out, DIM, IND);
  // --- MLP 2 ---
  ln_kernel<false><<<B_*NQ, 256, 0, stream>>>(c_out, ln_w, ln_b, Tb, nullptr);
  gemm_bt<128,0,true,true ><<<dim3(B_*NQ/128, HID/128), 256, 0, stream>>>(Tb, w12t, m2_b1, Hb, IND, HID);
  gemm_bt<64,2,true,false,2><<<dim3(B_*NQ/128, IND/64), 256, 0, stream>>>(Hb, w22t, m2_b2, c_out, HID, IND);
}